// Round 10
// baseline (5586.919 us; speedup 1.0000x reference)
//
#include <hip/hip_runtime.h>
#include <hip/hip_fp16.h>

#define B_   128
#define L_   1024
#define DIN  64
#define H_   512
#define DOUT 64

typedef _Float16 half8 __attribute__((ext_vector_type(8)));
typedef float    f32x4 __attribute__((ext_vector_type(4)));

#define FSTR 16            // flag stride in ints (64B)
#define SPIN_CAP (1<<16)   // gate cap: loud failure, no hang
#define POLL_CAP (1<<14)   // value-poll cap
#define POISON   0x7C00u   // f16 +inf — tanh outputs in [-1,1] never equal it

#define MFMA16(a,b,c) __builtin_amdgcn_mfma_f32_16x16x32_f16((a),(b),(c),0,0,0)
#define PINH8(x) asm volatile("" : "+v"(x))
#define AGENT_ST(p, v) __hip_atomic_store((p), (v), __ATOMIC_RELAXED, __HIP_MEMORY_SCOPE_AGENT)
#define AGENT_LD(p)    __hip_atomic_load((p), __ATOMIC_RELAXED, __HIP_MEMORY_SCOPE_AGENT)
#define WAITV(n) asm volatile("s_waitcnt vmcnt(" #n ")" ::: "memory")
#define PIN4(a,b,c,d) asm volatile("" : "+v"(a), "+v"(b), "+v"(c), "+v"(d))
#define PIN16(f) asm volatile("" : "+v"(f[0]), "+v"(f[1]), "+v"(f[2]), "+v"(f[3]), \
    "+v"(f[4]), "+v"(f[5]), "+v"(f[6]), "+v"(f[7]), "+v"(f[8]), "+v"(f[9]), \
    "+v"(f[10]), "+v"(f[11]), "+v"(f[12]), "+v"(f[13]), "+v"(f[14]), "+v"(f[15]))

// ---------------- init: poison rings (8 slots) + reset ctrs ----------------
__global__ void k_init(int* flags, unsigned int* hx0u, unsigned int* hx1u) {
    int i = blockIdx.x * blockDim.x + threadIdx.x;
    const int NR = 8 * 8 * 16 * H_ / 2;   // 262144 uint32 per ring
    if (i < NR) { hx0u[i] = 0x7C007C00u; hx1u[i] = 0x7C007C00u; }
    if (i < 128) flags[i * FSTR] = -1;
}

// ---------------- cast weights to f16 + bias sums ----------------
__global__ void k_prep_w(const float* __restrict__ whh0, const float* __restrict__ wih1,
                         const float* __restrict__ whh1, const float* __restrict__ wout,
                         const float* __restrict__ bih0, const float* __restrict__ bhh0,
                         const float* __restrict__ bih1, const float* __restrict__ bhh1,
                         _Float16* __restrict__ o0, _Float16* __restrict__ o1,
                         _Float16* __restrict__ o2, _Float16* __restrict__ o3,
                         float* __restrict__ b0s, float* __restrict__ b1s) {
    const int NW = H_ * H_;
    const int total = 3 * NW + DOUT * H_ + 2 * H_;
    int i  = blockIdx.x * blockDim.x + threadIdx.x;
    int st = gridDim.x * blockDim.x;
    for (; i < total; i += st) {
        if      (i < NW)            o0[i]          = (_Float16)whh0[i];
        else if (i < 2 * NW)        o1[i - NW]     = (_Float16)wih1[i - NW];
        else if (i < 3 * NW)        o2[i - 2 * NW] = (_Float16)whh1[i - 2 * NW];
        else if (i < 3 * NW + DOUT * H_) o3[i - 3 * NW] = (_Float16)wout[i - 3 * NW];
        else if (i < 3 * NW + DOUT * H_ + H_) {
            int j = i - (3 * NW + DOUT * H_);
            b0s[j] = bih0[j] + bhh0[j];
        } else {
            int j = i - (3 * NW + DOUT * H_ + H_);
            b1s[j] = bih1[j] + bhh1[j];
        }
    }
}

// ---------------- wcomb[g][d] = sum_h W_ih0[g][h] * W_in[h][d] ----------------
__global__ void k_wcomb(const float* __restrict__ wih0, const float* __restrict__ win,
                        _Float16* __restrict__ o) {
    int g = blockIdx.x;    // 512
    int d = threadIdx.x;   // 64
    float acc = 0.f;
    for (int h = 0; h < H_; ++h)
        acc += wih0[g * H_ + h] * win[h * DIN + d];
    o[g * DIN + d] = (_Float16)acc;
}

// ---------------- helpers ----------------
__device__ __forceinline__ int spin_geq(const int* fp, int tgt, int cached) {
    if (cached >= tgt) return cached;
    int v = AGENT_LD(fp);
    int it = 0;
    while (v < tgt && ++it < SPIN_CAP) v = AGENT_LD(fp);
    return v;
}

__device__ __forceinline__ float tanh_fast(float v) {
    float e = __expf(2.f * v);
    return 1.f - 2.f / (e + 1.f);
}

__device__ __forceinline__ void st16_sc(void* p, half8 v) {
    asm volatile("global_store_dwordx4 %0, %1, off sc0 sc1" :: "v"(p), "v"(v) : "memory");
}

// u prefetch: 4 x 16B plain loads at +0,16,128,144. NO wait (FIFO-tracked by WAITV).
__device__ __forceinline__ void ldu_nw(const void* p, f32x4& a, f32x4& b, f32x4& c, f32x4& d) {
    asm volatile(
        "global_load_dwordx4 %0, %4, off\n\t"
        "global_load_dwordx4 %1, %4, off offset:16\n\t"
        "global_load_dwordx4 %2, %4, off offset:128\n\t"
        "global_load_dwordx4 %3, %4, off offset:144"
        : "=&v"(a), "=&v"(b), "=&v"(c), "=&v"(d) : "v"(p) : "memory");
}

// 16 x 16B sc loads from base + i*64B, NO internal wait
#define LD16_BODY(TAIL)                                                       \
    asm volatile(                                                             \
        "global_load_dwordx4 %0, %16, off sc0 sc1\n\t"                        \
        "global_load_dwordx4 %1, %16, off offset:64 sc0 sc1\n\t"              \
        "global_load_dwordx4 %2, %16, off offset:128 sc0 sc1\n\t"             \
        "global_load_dwordx4 %3, %16, off offset:192 sc0 sc1\n\t"             \
        "global_load_dwordx4 %4, %16, off offset:256 sc0 sc1\n\t"             \
        "global_load_dwordx4 %5, %16, off offset:320 sc0 sc1\n\t"             \
        "global_load_dwordx4 %6, %16, off offset:384 sc0 sc1\n\t"             \
        "global_load_dwordx4 %7, %16, off offset:448 sc0 sc1\n\t"             \
        "global_load_dwordx4 %8, %16, off offset:512 sc0 sc1\n\t"             \
        "global_load_dwordx4 %9, %16, off offset:576 sc0 sc1\n\t"             \
        "global_load_dwordx4 %10, %16, off offset:640 sc0 sc1\n\t"            \
        "global_load_dwordx4 %11, %16, off offset:704 sc0 sc1\n\t"            \
        "global_load_dwordx4 %12, %16, off offset:768 sc0 sc1\n\t"            \
        "global_load_dwordx4 %13, %16, off offset:832 sc0 sc1\n\t"            \
        "global_load_dwordx4 %14, %16, off offset:896 sc0 sc1\n\t"            \
        "global_load_dwordx4 %15, %16, off offset:960 sc0 sc1" TAIL           \
        : "=&v"(f[0]), "=&v"(f[1]), "=&v"(f[2]), "=&v"(f[3]),                 \
          "=&v"(f[4]), "=&v"(f[5]), "=&v"(f[6]), "=&v"(f[7]),                 \
          "=&v"(f[8]), "=&v"(f[9]), "=&v"(f[10]), "=&v"(f[11]),               \
          "=&v"(f[12]), "=&v"(f[13]), "=&v"(f[14]), "=&v"(f[15])              \
        : "v"(base)                                                           \
        : "memory")

__device__ __forceinline__ void ld16_nw(const _Float16* base, half8 f[16]) {
    LD16_BODY("");
}
__device__ __forceinline__ void ld16_w(const _Float16* base, half8 f[16]) {
    LD16_BODY("\n\ts_waitcnt vmcnt(0)");
}

// full poll (waits internally): rare path + G3
__device__ __forceinline__ void poll16(const _Float16* base, half8 f[16]) {
    int it = 0;
    for (;;) {
        ld16_w(base, f);
        int ok = 1;
#pragma unroll
        for (int i = 0; i < 16; ++i) {
            union { half8 h; unsigned short s[8]; } u; u.h = f[i];
            ok &= (u.s[0] != POISON);
        }
        if (__all(ok) || ++it > POLL_CAP) break;
    }
}

// validate already-loaded frags; rare re-poll on poison
__device__ __forceinline__ void validate16(const _Float16* base, half8 f[16]) {
    int ok = 1;
#pragma unroll
    for (int i = 0; i < 16; ++i) {
        union { half8 h; unsigned short s[8]; } u; u.h = f[i];
        ok &= (u.s[0] != POISON);
    }
    if (!__all(ok)) poll16(base, f);
}

// ---------------- fused persistent pipeline: poisoned slots + issue-early/validate-late ----
// grid = 112 x 256 thr: g = bid&7, role = bid>>3.
//   role 0..3  : L0, cols 128*role          role 4..11 : L1 (xw1 inline), cols 64*(role-4)
//   role 12,13 : G3 parity blocks
// Rings hx0/hx1: [8 groups][8 slots][16][512] f16, 16B-chunk stores.
// Protocol (proven r8): poison slot t+1 early in step t, acked (vmcnt, in-order) before
// step-t data store issues => consumer seeing step-(t-1) data implies slot-t poison landed.
// Overwrite gate: consumers' ctr >= t-6 before poisoning slot holding t-7 data.
__global__ __launch_bounds__(256, 1)
void k_pipeline(const float* __restrict__ u,
                const _Float16* __restrict__ wcomb,   // [512][64]
                const _Float16* __restrict__ whh0w,   // [512][512]
                const float* __restrict__ b0s,
                const _Float16* __restrict__ wih1w,   // [512][512]
                const _Float16* __restrict__ whh1w,   // [512][512]
                const float* __restrict__ b1s,
                const _Float16* __restrict__ woutw,   // [64][512]
                float* __restrict__ out,              // [B_*L_][64] fp32
                _Float16* __restrict__ hx0,
                _Float16* __restrict__ hx1,
                int* __restrict__ flags) {            // ctr[bid] at flags[bid*FSTR]
    const int bid = blockIdx.x;
    const int g = bid & 7, role = bid >> 3;
    const int tid = threadIdx.x;
    const int l = tid & 63, w = tid >> 6;
    const int l15 = l & 15, lg = l >> 4, kofs = lg * 8;
    const int b0 = g * 16;
    _Float16* hx0g = hx0 + (size_t)g * (8 * 16 * H_);
    _Float16* hx1g = hx1 + (size_t)g * (8 * 16 * H_);
    int* myctr = flags + bid * FSTR;

    __shared__ _Float16 hlt[16][136];

    union { unsigned short s[8]; half8 h; } pv;
#pragma unroll
    for (int i = 0; i < 8; ++i) pv.s[i] = POISON;
    const half8 poisonv = pv.h;

    if (role < 4) {
        // ================= L0 =================
        const int s = role;
        const int col0 = s * 128 + w * 32;
        half8 whf[2][16], wcf[2][2];
#pragma unroll
        for (int nt = 0; nt < 2; ++nt) {
            const int n = col0 + nt * 16 + l15;
#pragma unroll
            for (int kt = 0; kt < 16; ++kt) {
                whf[nt][kt] = *(const half8*)(whh0w + (size_t)n * H_ + kt * 32 + kofs);
                PINH8(whf[nt][kt]);
            }
#pragma unroll
            for (int kt = 0; kt < 2; ++kt) {
                wcf[nt][kt] = *(const half8*)(wcomb + (size_t)n * DIN + kt * 32 + kofs);
                PINH8(wcf[nt][kt]);
            }
        }
        const float bv0 = b0s[col0 + l15], bv1 = b0s[col0 + 16 + l15];
        // h0 consumers: L0 roles 0-3 + L1 roles 4-11
        const int* gatep = (tid < 12) ? flags + (g + 8 * tid) * FSTR : nullptr;
        int gc = -1;
        const int prow = tid >> 4, pc8 = tid & 15;

        for (int t = 0; t < L_; ++t) {
            if (t >= 7 && gatep) gc = spin_geq(gatep, t - 6, gc);
            __syncthreads();                                      // B0
            // issue FIFO: poison(1) -> u(4) -> h(16); no compiler mem-ops until WAITV
            if (t + 1 < L_)
                st16_sc(hx0g + (size_t)((t + 1) & 7) * (16 * H_)
                        + (size_t)prow * H_ + s * 128 + pc8 * 8, poisonv);
            f32x4 u0, u1, u2, u3;
            ldu_nw(u + ((size_t)(b0 + l15) * L_ + t) * DIN + kofs, u0, u1, u2, u3);
            half8 a[16];
            const _Float16* hbase = hx0g + (size_t)((t - 1) & 7) * (16 * H_)
                                  + (size_t)l15 * H_ + kofs;
            if (t > 0) { ld16_nw(hbase, a); WAITV(16); } else { WAITV(0); }
            PIN4(u0, u1, u2, u3);                                 // u valid here
            half8 ua[2];
#pragma unroll
            for (int j = 0; j < 4; ++j) {
                ua[0][j] = (_Float16)u0[j]; ua[0][4 + j] = (_Float16)u1[j];
                ua[1][j] = (_Float16)u2[j]; ua[1][4 + j] = (_Float16)u3[j];
            }
            f32x4 acc0 = (f32x4){bv0, bv0, bv0, bv0};
            f32x4 acc1 = (f32x4){bv1, bv1, bv1, bv1};
#pragma unroll
            for (int kt = 0; kt < 2; ++kt) {                      // h still in flight
                acc0 = MFMA16(ua[kt], wcf[0][kt], acc0);
                acc1 = MFMA16(ua[kt], wcf[1][kt], acc1);
            }
            if (t > 0) {
                WAITV(0);
                PIN16(a);
                validate16(hbase, a);
#pragma unroll
                for (int kt = 0; kt < 16; ++kt) {
                    acc0 = MFMA16(a[kt], whf[0][kt], acc0);
                    acc1 = MFMA16(a[kt], whf[1][kt], acc1);
                }
            }
            _Float16 th0[4], th1[4];
#pragma unroll
            for (int r = 0; r < 4; ++r) {
                th0[r] = (_Float16)tanh_fast(acc0[r]);
                th1[r] = (_Float16)tanh_fast(acc1[r]);
            }
            __syncthreads();                                      // B1
#pragma unroll
            for (int r = 0; r < 4; ++r) {
                hlt[lg * 4 + r][w * 32 + l15]      = th0[r];
                hlt[lg * 4 + r][w * 32 + 16 + l15] = th1[r];
            }
            __syncthreads();                                      // B2
            {   // publish (poison for t+1 already acked at WAITV(16) point)
                half8 ch = *(const half8*)&hlt[prow][pc8 * 8];
                st16_sc(hx0g + (size_t)(t & 7) * (16 * H_)
                        + (size_t)prow * H_ + s * 128 + pc8 * 8, ch);
            }
            if (tid == 0) AGENT_ST(myctr, t);
        }
    } else if (role < 12) {
        // ================= L1 (xw1 inline) =================
        const int s = role - 4;
        const int n = s * 64 + w * 16 + l15;
        half8 wif[16], whf[16];
#pragma unroll
        for (int kt = 0; kt < 16; ++kt) {
            wif[kt] = *(const half8*)(wih1w + (size_t)n * H_ + kt * 32 + kofs);
            PINH8(wif[kt]);
            whf[kt] = *(const half8*)(whh1w + (size_t)n * H_ + kt * 32 + kofs);
            PINH8(whf[kt]);
        }
        const float bv = b1s[n];
        // h1 consumers: L1 roles 4-11 + G3 roles 12,13
        const int* gatep = (tid < 10) ? flags + (g + 8 * (4 + tid)) * FSTR : nullptr;
        int gc = -1;
        const int prow = tid >> 3, pc8 = tid & 7;   // tid<128 own the 128 chunks

        for (int t = 0; t < L_; ++t) {
            if (t >= 7 && gatep) gc = spin_geq(gatep, t - 6, gc);
            __syncthreads();                                      // B0
            if (t + 1 < L_ && tid < 128)
                st16_sc(hx1g + (size_t)((t + 1) & 7) * (16 * H_)
                        + (size_t)prow * H_ + s * 64 + pc8 * 8, poisonv);
            half8 a1[16], a0[16];
            const _Float16* h1base = hx1g + (size_t)((t - 1) & 7) * (16 * H_)
                                   + (size_t)l15 * H_ + kofs;
            const _Float16* h0base = hx0g + (size_t)(t & 7) * (16 * H_)
                                   + (size_t)l15 * H_ + kofs;
            if (t > 0) ld16_nw(h1base, a1);
            ld16_nw(h0base, a0);
            f32x4 acch = (f32x4){0.f, 0.f, 0.f, 0.f};
            if (t > 0) {
                WAITV(16);                                        // poison+h1 retired
                PIN16(a1);
                validate16(h1base, a1);
#pragma unroll
                for (int kt = 0; kt < 16; ++kt)                   // h0 still in flight
                    acch = MFMA16(a1[kt], whf[kt], acch);
            }
            WAITV(0);
            PIN16(a0);
            validate16(h0base, a0);
            f32x4 accx = (f32x4){bv, bv, bv, bv};
#pragma unroll
            for (int kt = 0; kt < 16; ++kt)
                accx = MFMA16(a0[kt], wif[kt], accx);
            _Float16 th[4];
#pragma unroll
            for (int r = 0; r < 4; ++r) th[r] = (_Float16)tanh_fast(accx[r] + acch[r]);
            __syncthreads();                                      // B1
#pragma unroll
            for (int r = 0; r < 4; ++r)
                hlt[lg * 4 + r][w * 16 + l15] = th[r];
            __syncthreads();                                      // B2
            if (tid < 128) {
                half8 ch = *(const half8*)&hlt[prow][pc8 * 8];
                st16_sc(hx1g + (size_t)(t & 7) * (16 * H_)
                        + (size_t)prow * H_ + s * 64 + pc8 * 8, ch);
            }
            if (tid == 0) AGENT_ST(myctr, t);
        }
    } else {
        // ================= G3 parity blocks =================
        const int p = role - 12;
        const int n = w * 16 + l15;
        half8 wof[16];
#pragma unroll
        for (int kt = 0; kt < 16; ++kt) {
            wof[kt] = *(const half8*)(woutw + (size_t)n * H_ + kt * 32 + kofs);
            PINH8(wof[kt]);
        }
        for (int t = p; t < L_; t += 2) {
            half8 a[16];
            poll16(hx1g + (size_t)(t & 7) * (16 * H_) + (size_t)l15 * H_ + kofs, a);
            f32x4 acc = (f32x4){0.f, 0.f, 0.f, 0.f};
#pragma unroll
            for (int kt = 0; kt < 16; ++kt)
                acc = MFMA16(a[kt], wof[kt], acc);
            __syncthreads();                 // all waves' reads for step t complete
            if (tid == 0) AGENT_ST(myctr, t);
#pragma unroll
            for (int r = 0; r < 4; ++r)
                out[((size_t)(b0 + lg * 4 + r) * L_ + t) * DOUT + n] = acc[r];
        }
    }
}

// ---------------- launch ----------------
extern "C" void kernel_launch(void* const* d_in, const int* in_sizes, int n_in,
                              void* d_out, int out_size, void* d_ws, size_t ws_size,
                              hipStream_t stream) {
    const float* u    = (const float*)d_in[0];
    const float* Win  = (const float*)d_in[1];
    const float* Wih0 = (const float*)d_in[2];
    const float* Whh0 = (const float*)d_in[3];
    const float* bih0 = (const float*)d_in[4];
    const float* bhh0 = (const float*)d_in[5];
    const float* Wih1 = (const float*)d_in[6];
    const float* Whh1 = (const float*)d_in[7];
    const float* bih1 = (const float*)d_in[8];
    const float* bhh1 = (const float*)d_in[9];
    const float* Wout = (const float*)d_in[10];
    (void)in_sizes; (void)n_in; (void)out_size; (void)ws_size;

    char* ws = (char*)d_ws;
    size_t off = 0;
    auto alloc = [&](size_t bytes) {
        char* p = ws + off;
        off += (bytes + 255) & ~(size_t)255;
        return p;
    };
    // total workspace ~4.3 MB
    _Float16* wcomb = (_Float16*)alloc((size_t)H_ * DIN * 2);
    _Float16* whh0h = (_Float16*)alloc((size_t)H_ * H_ * 2);
    _Float16* wih1h = (_Float16*)alloc((size_t)H_ * H_ * 2);
    _Float16* whh1h = (_Float16*)alloc((size_t)H_ * H_ * 2);
    _Float16* wouth = (_Float16*)alloc((size_t)DOUT * H_ * 2);
    float*    b0s   = (float*)alloc(H_ * 4);
    float*    b1s   = (float*)alloc(H_ * 4);
    _Float16* hx0   = (_Float16*)alloc((size_t)8 * 8 * 16 * H_ * 2);
    _Float16* hx1   = (_Float16*)alloc((size_t)8 * 8 * 16 * H_ * 2);
    int*      flags = (int*)alloc(128 * FSTR * 4);

    k_init<<<1024, 256, 0, stream>>>(flags, (unsigned int*)hx0, (unsigned int*)hx1);
    k_prep_w<<<1024, 256, 0, stream>>>(Whh0, Wih1, Whh1, Wout, bih0, bhh0, bih1, bhh1,
                                       whh0h, wih1h, whh1h, wouth, b0s, b1s);
    k_wcomb<<<512, 64, 0, stream>>>(Wih0, Win, wcomb);

    k_pipeline<<<112, 256, 0, stream>>>(u, wcomb, whh0h, b0s, wih1h, whh1h, b1s, wouth,
                                        (float*)d_out, hx0, hx1, flags);
}

// Round 12
// 3139.398 us; speedup vs baseline: 1.7796x; 1.7796x over previous
//
#include <hip/hip_runtime.h>
#include <hip/hip_fp16.h>

#define B_   128
#define L_   1024
#define DIN  64
#define H_   512
#define DOUT 64

typedef _Float16 half8 __attribute__((ext_vector_type(8)));
typedef float    f32x4 __attribute__((ext_vector_type(4)));

#define FSTR 16
#define SPIN_CAP (1<<16)
#define POLL_CAP (1<<15)
#define POISON   0x7C00u   // f16 +inf; tanh outputs in [-1,1] never equal it

#define MFMA16(a,b,c) __builtin_amdgcn_mfma_f32_16x16x32_f16((a),(b),(c),0,0,0)
#define PINH8(x) asm volatile("" : "+v"(x))
#define AGENT_ST(p, v) __hip_atomic_store((p), (v), __ATOMIC_RELAXED, __HIP_MEMORY_SCOPE_AGENT)
#define AGENT_LD(p)    __hip_atomic_load((p), __ATOMIC_RELAXED, __HIP_MEMORY_SCOPE_AGENT)

// ---------------- init: poison both rings + reset ctrs ----------------
__global__ void k_init(int* flags, unsigned int* hx0u, unsigned int* hx1u) {
    int i = blockIdx.x * blockDim.x + threadIdx.x;
    const int NR = 8 * 8 * 8192 / 2;   // 262144 u32 per ring
    if (i < NR) { hx0u[i] = 0x7C007C00u; hx1u[i] = 0x7C007C00u; }
    if (i < 64) flags[i * FSTR] = -1;
}

// ---------------- cast weights to f16 + bias sums ----------------
__global__ void k_prep_w(const float* __restrict__ whh0, const float* __restrict__ wih1,
                         const float* __restrict__ whh1, const float* __restrict__ wout,
                         const float* __restrict__ bih0, const float* __restrict__ bhh0,
                         const float* __restrict__ bih1, const float* __restrict__ bhh1,
                         _Float16* __restrict__ o0, _Float16* __restrict__ o1,
                         _Float16* __restrict__ o2, _Float16* __restrict__ o3,
                         float* __restrict__ b0s, float* __restrict__ b1s) {
    const int NW = H_ * H_;
    const int total = 3 * NW + DOUT * H_ + 2 * H_;
    int i  = blockIdx.x * blockDim.x + threadIdx.x;
    int st = gridDim.x * blockDim.x;
    for (; i < total; i += st) {
        if      (i < NW)            o0[i]          = (_Float16)whh0[i];
        else if (i < 2 * NW)        o1[i - NW]     = (_Float16)wih1[i - NW];
        else if (i < 3 * NW)        o2[i - 2 * NW] = (_Float16)whh1[i - 2 * NW];
        else if (i < 3 * NW + DOUT * H_) o3[i - 3 * NW] = (_Float16)wout[i - 3 * NW];
        else if (i < 3 * NW + DOUT * H_ + H_) {
            int j = i - (3 * NW + DOUT * H_);
            b0s[j] = bih0[j] + bhh0[j];
        } else {
            int j = i - (3 * NW + DOUT * H_ + H_);
            b1s[j] = bih1[j] + bhh1[j];
        }
    }
}

// ---------------- wcomb[g][d] = sum_h W_ih0[g][h] * W_in[h][d] ----------------
__global__ void k_wcomb(const float* __restrict__ wih0, const float* __restrict__ win,
                        _Float16* __restrict__ o) {
    int g = blockIdx.x;    // 512
    int d = threadIdx.x;   // 64
    float acc = 0.f;
    for (int h = 0; h < H_; ++h)
        acc += wih0[g * H_ + h] * win[h * DIN + d];
    o[g * DIN + d] = (_Float16)acc;
}

// ---------------- helpers ----------------
__device__ __forceinline__ int spin_geq(const int* fp, int tgt, int cached) {
    if (cached >= tgt) return cached;
    int v = AGENT_LD(fp);
    int it = 0;
    while (v < tgt && ++it < SPIN_CAP) v = AGENT_LD(fp);
    return v;
}

__device__ __forceinline__ float tanh_fast(float v) {
    float e = __expf(2.f * v);
    return 1.f - 2.f / (e + 1.f);
}

__device__ __forceinline__ void st16_sc(void* p, half8 v) {
    asm volatile("global_store_dwordx4 %0, %1, off sc0 sc1" :: "v"(p), "v"(v) : "memory");
}

// 2 coherent 16B loads, internal vmcnt(0): outputs valid at asm end
__device__ __forceinline__ void ld2_sc(const _Float16* p1, const _Float16* p2,
                                       half8& a, half8& b) {
    asm volatile(
        "global_load_dwordx4 %0, %2, off sc0 sc1\n\t"
        "global_load_dwordx4 %1, %3, off sc0 sc1\n\t"
        "s_waitcnt vmcnt(0)"
        : "=&v"(a), "=&v"(b) : "v"(p1), "v"(p2) : "memory");
}
// 4 coherent 16B loads, internal vmcnt(0)
__device__ __forceinline__ void ld4_sc(const _Float16* p1, const _Float16* p2,
                                       const _Float16* p3, const _Float16* p4,
                                       half8& a, half8& b, half8& c, half8& d) {
    asm volatile(
        "global_load_dwordx4 %0, %4, off sc0 sc1\n\t"
        "global_load_dwordx4 %1, %5, off sc0 sc1\n\t"
        "global_load_dwordx4 %2, %6, off sc0 sc1\n\t"
        "global_load_dwordx4 %3, %7, off sc0 sc1\n\t"
        "s_waitcnt vmcnt(0)"
        : "=&v"(a), "=&v"(b), "=&v"(c), "=&v"(d)
        : "v"(p1), "v"(p2), "v"(p3), "v"(p4) : "memory");
}

__device__ __forceinline__ int chunk_ok(half8 h) {
    union { half8 v; unsigned short s[8]; } u; u.v = h;
    return u.s[0] != POISON;   // each 16B chunk written by ONE 16B store
}

// ---------------- fused persistent pipeline: cooperative-load poisoned slots ----------------
// 64 blocks x 512 thr:
//  bid 0..15 : L0  g=bid>>1, d=bid&1, cols [d*256,+256)
//  bid 16..47: L1  g=(bid-16)>>2, e=(bid-16)&3, cols [e*128,+128)
//  bid 48..63: G3  g=(bid-48)>>1, parity q=(bid-48)&1
// Rings hx0/hx1: [8 g][8 slots][16][512] f16, 16B chunks. Consumers poll 1-2 chunks/thread
// (single loads), broadcast via LDS; ctr published after input-consumed barrier; producers
// poison slot t+2 early (acked by pre-publish vmcnt(0) drain); gates every 4 steps @ t-3.
__global__ __launch_bounds__(512, 2)
void k_pipeline(const float* __restrict__ u,
                const _Float16* __restrict__ wcomb,
                const _Float16* __restrict__ whh0w,
                const float* __restrict__ b0s,
                const _Float16* __restrict__ wih1w,
                const _Float16* __restrict__ whh1w,
                const float* __restrict__ b1s,
                const _Float16* __restrict__ woutw,
                float* __restrict__ out,
                _Float16* __restrict__ hx0,
                _Float16* __restrict__ hx1,
                int* __restrict__ flags) {
    const int bid = blockIdx.x;
    const int tid = threadIdx.x;
    const int l = tid & 63, w = tid >> 6;          // 8 waves
    const int l15 = l & 15, lg = l >> 4, kofs = lg * 8;

    __shared__ _Float16 pb0[16][520];
    __shared__ _Float16 pb1[16][520];
    __shared__ _Float16 hlt[16][264];

    union { unsigned short s[8]; half8 h; } pv;
#pragma unroll
    for (int i = 0; i < 8; ++i) pv.s[i] = POISON;
    const half8 poisonv = pv.h;

    // cooperative read-chunk coords (full 16KB slot, 2 chunks/thread)
    const int rof1 = (tid >> 6) * 512 + (tid & 63) * 8;
    const int rof2 = rof1 + 4096;                 // rows +8
    const int prow1 = tid >> 6, prow2 = prow1 + 8, pcol = (tid & 63) * 8;

    if (bid < 16) {
        // ================= L0 =================
        const int g = bid >> 1, d = bid & 1;
        const int b0 = g * 16;
        const int colw = d * 256 + w * 32;
        half8 whf[2][16], wcf[2][2]; float bv[2];
#pragma unroll
        for (int nt = 0; nt < 2; ++nt) {
            const int n = colw + nt * 16 + l15;
#pragma unroll
            for (int kt = 0; kt < 16; ++kt) {
                whf[nt][kt] = *(const half8*)(whh0w + (size_t)n * H_ + kt * 32 + kofs);
                PINH8(whf[nt][kt]);
            }
#pragma unroll
            for (int kt = 0; kt < 2; ++kt) {
                wcf[nt][kt] = *(const half8*)(wcomb + (size_t)n * DIN + kt * 32 + kofs);
                PINH8(wcf[nt][kt]);
            }
            bv[nt] = b0s[n];
        }
        _Float16* ring = hx0 + (size_t)g * 65536;
        const int oofs = (tid >> 5) * 512 + d * 256 + (tid & 31) * 8;   // own chunk
        // gates: partner L0 + 4 L1 of group
        const int* gate = (tid == 0) ? flags + (bid ^ 1) * FSTR
                        : (tid <= 4) ? flags + (16 + g * 4 + (tid - 1)) * FSTR : nullptr;
        int gcache = -1;

        for (int t = 0; t < L_; ++t) {
            if (t >= 4 && (t & 3) == 0 && gate) gcache = spin_geq(gate, t - 3, gcache);
            __syncthreads();                                    // B0
            st16_sc(ring + (size_t)((t + 2) & 7) * 8192 + oofs, poisonv);
            // u part (plain cached loads, compiler-managed waits)
            const float* up = u + ((size_t)(b0 + l15) * L_ + t) * DIN + kofs;
            f32x4 u0 = *(const f32x4*)(up);
            f32x4 u1 = *(const f32x4*)(up + 4);
            f32x4 u2 = *(const f32x4*)(up + 32);
            f32x4 u3 = *(const f32x4*)(up + 36);
            half8 ua0, ua1;
#pragma unroll
            for (int j = 0; j < 4; ++j) {
                ua0[j] = (_Float16)u0[j]; ua0[4 + j] = (_Float16)u1[j];
                ua1[j] = (_Float16)u2[j]; ua1[4 + j] = (_Float16)u3[j];
            }
            f32x4 acc0 = (f32x4){bv[0], bv[0], bv[0], bv[0]};
            f32x4 acc1 = (f32x4){bv[1], bv[1], bv[1], bv[1]};
            acc0 = MFMA16(ua0, wcf[0][0], acc0); acc0 = MFMA16(ua1, wcf[0][1], acc0);
            acc1 = MFMA16(ua0, wcf[1][0], acc1); acc1 = MFMA16(ua1, wcf[1][1], acc1);
            if (t > 0) {   // cooperative poll+load h0_{t-1} into LDS
                const _Float16* sb = ring + (size_t)((t - 1) & 7) * 8192;
                half8 c1, c2; int it = 0;
                for (;;) {
                    ld2_sc(sb + rof1, sb + rof2, c1, c2);
                    if ((chunk_ok(c1) & chunk_ok(c2)) || ++it > POLL_CAP) break;
                }
                *(half8*)&pb0[prow1][pcol] = c1;
                *(half8*)&pb0[prow2][pcol] = c2;
            }
            __syncthreads();                                    // B1: inputs in LDS
            if (tid == 0) AGENT_ST(flags + bid * FSTR, t);      // inputs consumed
            if (t > 0) {
#pragma unroll
                for (int kt = 0; kt < 16; ++kt) {
                    half8 a = *(const half8*)&pb0[l15][kt * 32 + kofs];
                    acc0 = MFMA16(a, whf[0][kt], acc0);
                    acc1 = MFMA16(a, whf[1][kt], acc1);
                }
            }
            _Float16 th0[4], th1[4];
#pragma unroll
            for (int r = 0; r < 4; ++r) {
                th0[r] = (_Float16)tanh_fast(acc0[r]);
                th1[r] = (_Float16)tanh_fast(acc1[r]);
            }
#pragma unroll
            for (int r = 0; r < 4; ++r) {
                hlt[lg * 4 + r][w * 32 + l15]      = th0[r];
                hlt[lg * 4 + r][w * 32 + 16 + l15] = th1[r];
            }
            __syncthreads();                                    // B2: hlt complete
            half8 ch = *(const half8*)&hlt[tid >> 5][(tid & 31) * 8];
            asm volatile("s_waitcnt vmcnt(0)" ::: "memory");    // poison acked (~free)
            st16_sc(ring + (size_t)(t & 7) * 8192 + oofs, ch);
        }
    } else if (bid < 48) {
        // ================= L1 =================
        const int idx = bid - 16;
        const int g = idx >> 2, e = idx & 3;
        const int n = e * 128 + w * 16 + l15;
        half8 wif[16], whf1[16];
#pragma unroll
        for (int kt = 0; kt < 16; ++kt) {
            wif[kt] = *(const half8*)(wih1w + (size_t)n * H_ + kt * 32 + kofs);
            PINH8(wif[kt]);
            whf1[kt] = *(const half8*)(whh1w + (size_t)n * H_ + kt * 32 + kofs);
            PINH8(whf1[kt]);
        }
        const float bv = b1s[n];
        _Float16* ring0 = hx0 + (size_t)g * 65536;
        _Float16* ring1 = hx1 + (size_t)g * 65536;
        const int oofs = (tid >> 4) * 512 + e * 128 + (tid & 15) * 8;   // own chunk (tid<256)
        // gates: 3 L1 partners + 2 G3
        const int* gate = nullptr;
        if (tid < 3)       gate = flags + (16 + g * 4 + (tid < e ? tid : tid + 1)) * FSTR;
        else if (tid < 5)  gate = flags + (48 + g * 2 + (tid - 3)) * FSTR;
        int gcache = -1;

        for (int t = 0; t < L_; ++t) {
            if (t >= 4 && (t & 3) == 0 && gate) gcache = spin_geq(gate, t - 3, gcache);
            __syncthreads();                                    // B0
            if (tid < 256)
                st16_sc(ring1 + (size_t)((t + 2) & 7) * 8192 + oofs, poisonv);
            const _Float16* s0 = ring0 + (size_t)(t & 7) * 8192;
            if (t > 0) {
                const _Float16* s1 = ring1 + (size_t)((t - 1) & 7) * 8192;
                half8 d1a, d1b, d0a, d0b; int it = 0;
                for (;;) {
                    ld4_sc(s1 + rof1, s1 + rof2, s0 + rof1, s0 + rof2, d1a, d1b, d0a, d0b);
                    if ((chunk_ok(d1a) & chunk_ok(d1b) & chunk_ok(d0a) & chunk_ok(d0b))
                        || ++it > POLL_CAP) break;
                }
                *(half8*)&pb1[prow1][pcol] = d1a;
                *(half8*)&pb1[prow2][pcol] = d1b;
                *(half8*)&pb0[prow1][pcol] = d0a;
                *(half8*)&pb0[prow2][pcol] = d0b;
            } else {
                half8 d0a, d0b; int it = 0;
                for (;;) {
                    ld2_sc(s0 + rof1, s0 + rof2, d0a, d0b);
                    if ((chunk_ok(d0a) & chunk_ok(d0b)) || ++it > POLL_CAP) break;
                }
                *(half8*)&pb0[prow1][pcol] = d0a;
                *(half8*)&pb0[prow2][pcol] = d0b;
            }
            __syncthreads();                                    // B1
            if (tid == 0) AGENT_ST(flags + bid * FSTR, t);
            f32x4 acch = (f32x4){0.f, 0.f, 0.f, 0.f};
            if (t > 0) {
#pragma unroll
                for (int kt = 0; kt < 16; ++kt) {
                    half8 a1 = *(const half8*)&pb1[l15][kt * 32 + kofs];
                    acch = MFMA16(a1, whf1[kt], acch);
                }
            }
            f32x4 accx = (f32x4){bv, bv, bv, bv};
#pragma unroll
            for (int kt = 0; kt < 16; ++kt) {
                half8 a0 = *(const half8*)&pb0[l15][kt * 32 + kofs];
                accx = MFMA16(a0, wif[kt], accx);
            }
            _Float16 th[4];
#pragma unroll
            for (int r = 0; r < 4; ++r) th[r] = (_Float16)tanh_fast(accx[r] + acch[r]);
#pragma unroll
            for (int r = 0; r < 4; ++r)
                hlt[lg * 4 + r][w * 16 + l15] = th[r];
            __syncthreads();                                    // B2
            if (tid < 256) {
                half8 ch = *(const half8*)&hlt[tid >> 4][(tid & 15) * 8];
                asm volatile("s_waitcnt vmcnt(0)" ::: "memory");
                st16_sc(ring1 + (size_t)(t & 7) * 8192 + oofs, ch);
            }
        }
    } else {
        // ================= G3 (parity) =================
        const int idx = bid - 48;
        const int g = idx >> 1, q = idx & 1;
        const int b0 = g * 16;
        half8 wof[16];
        if (w < 4) {
            const int n = w * 16 + l15;
#pragma unroll
            for (int kt = 0; kt < 16; ++kt) {
                wof[kt] = *(const half8*)(woutw + (size_t)n * H_ + kt * 32 + kofs);
                PINH8(wof[kt]);
            }
        }
        const _Float16* ring1 = hx1 + (size_t)g * 65536;
        for (int t = q; t < L_; t += 2) {
            __syncthreads();                                    // protect pb1 reuse
            const _Float16* s = ring1 + (size_t)(t & 7) * 8192;
            half8 c1, c2; int it = 0;
            for (;;) {
                ld2_sc(s + rof1, s + rof2, c1, c2);
                if ((chunk_ok(c1) & chunk_ok(c2)) || ++it > POLL_CAP) break;
            }
            *(half8*)&pb1[prow1][pcol] = c1;
            *(half8*)&pb1[prow2][pcol] = c2;
            __syncthreads();
            if (tid == 0) AGENT_ST(flags + bid * FSTR, t);
            if (w < 4) {
                f32x4 acc = (f32x4){0.f, 0.f, 0.f, 0.f};
#pragma unroll
                for (int kt = 0; kt < 16; ++kt) {
                    half8 a = *(const half8*)&pb1[l15][kt * 32 + kofs];
                    acc = MFMA16(a, wof[kt], acc);
                }
                const int n = w * 16 + l15;
#pragma unroll
                for (int r = 0; r < 4; ++r)
                    out[((size_t)(b0 + lg * 4 + r) * L_ + t) * DOUT + n] = acc[r];
            }
        }
    }
}

// ---------------- launch ----------------
extern "C" void kernel_launch(void* const* d_in, const int* in_sizes, int n_in,
                              void* d_out, int out_size, void* d_ws, size_t ws_size,
                              hipStream_t stream) {
    const float* u    = (const float*)d_in[0];
    const float* Win  = (const float*)d_in[1];
    const float* Wih0 = (const float*)d_in[2];
    const float* Whh0 = (const float*)d_in[3];
    const float* bih0 = (const float*)d_in[4];
    const float* bhh0 = (const float*)d_in[5];
    const float* Wih1 = (const float*)d_in[6];
    const float* Whh1 = (const float*)d_in[7];
    const float* bih1 = (const float*)d_in[8];
    const float* bhh1 = (const float*)d_in[9];
    const float* Wout = (const float*)d_in[10];
    (void)in_sizes; (void)n_in; (void)out_size; (void)ws_size;

    char* ws = (char*)d_ws;
    size_t off = 0;
    auto alloc = [&](size_t bytes) {
        char* p = ws + off;
        off += (bytes + 255) & ~(size_t)255;
        return p;
    };
    // workspace ~4.8 MB
    _Float16* wcomb = (_Float16*)alloc((size_t)H_ * DIN * 2);
    _Float16* whh0h = (_Float16*)alloc((size_t)H_ * H_ * 2);
    _Float16* wih1h = (_Float16*)alloc((size_t)H_ * H_ * 2);
    _Float16* whh1h = (_Float16*)alloc((size_t)H_ * H_ * 2);
    _Float16* wouth = (_Float16*)alloc((size_t)DOUT * H_ * 2);
    float*    b0s   = (float*)alloc(H_ * 4);
    float*    b1s   = (float*)alloc(H_ * 4);
    _Float16* hx0   = (_Float16*)alloc((size_t)8 * 8 * 8192 * 2);
    _Float16* hx1   = (_Float16*)alloc((size_t)8 * 8 * 8192 * 2);
    int*      flags = (int*)alloc(64 * FSTR * 4);

    k_init<<<1024, 256, 0, stream>>>(flags, (unsigned int*)hx0, (unsigned int*)hx1);
    k_prep_w<<<1024, 256, 0, stream>>>(Whh0, Wih1, Whh1, Wout, bih0, bhh0, bih1, bhh1,
                                       whh0h, wih1h, whh1h, wouth, b0s, b1s);
    k_wcomb<<<512, 64, 0, stream>>>(Wih0, Win, wcomb);

    k_pipeline<<<64, 512, 0, stream>>>(u, wcomb, whh0h, b0s, wih1h, whh1h, b1s, wouth,
                                       (float*)d_out, hx0, hx1, flags);
}